// Round 6
// baseline (138.138 us; speedup 1.0000x reference)
//
#include <hip/hip_runtime.h>
#include <stdint.h>

#define B_ 4
#define C_ 128
#define H_ 128
#define W_ 128
#define HW 16384

typedef short short8 __attribute__((ext_vector_type(8)));
typedef float f32x2 __attribute__((ext_vector_type(2)));
typedef float f32x16 __attribute__((ext_vector_type(16)));

__device__ __forceinline__ unsigned pack_bf16(float lo, float hi) {
    unsigned ul = __float_as_uint(lo);
    unsigned uh = __float_as_uint(hi);
    ul = (ul + 0x7fffu + ((ul >> 16) & 1u)) >> 16;
    uh = (uh + 0x7fffu + ((uh >> 16) & 1u)) & 0xffff0000u;
    return uh | ul;
}

__device__ __forceinline__ unsigned cvtpk(float lo, float hi) {
    unsigned r;
    asm("v_cvt_pk_bf16_f32 %0, %1, %2" : "=v"(r) : "v"(lo), "v"(hi));
    return r;
}

__device__ __forceinline__ f32x2 pkmul(f32x2 a, f32x2 b) {
    f32x2 d;
    asm("v_pk_mul_f32 %0, %1, %2" : "=v"(d) : "v"(a), "v"(b));
    return d;
}
__device__ __forceinline__ f32x2 pkfma(f32x2 a, f32x2 b, f32x2 c) {
    f32x2 d;
    asm("v_pk_fma_f32 %0, %1, %2, %3" : "=v"(d) : "v"(a), "v"(b), "v"(c));
    return d;
}

__device__ __forceinline__ unsigned blend_pk(unsigned c0, unsigned c1, unsigned c2, unsigned c3,
                                             f32x2 G0, f32x2 G1, f32x2 G2, f32x2 G3) {
    f32x2 a0, a1, a2, a3;
    a0[0] = __uint_as_float(c0 << 16); a0[1] = __uint_as_float(c0 & 0xffff0000u);
    a1[0] = __uint_as_float(c1 << 16); a1[1] = __uint_as_float(c1 & 0xffff0000u);
    a2[0] = __uint_as_float(c2 << 16); a2[1] = __uint_as_float(c2 & 0xffff0000u);
    a3[0] = __uint_as_float(c3 << 16); a3[1] = __uint_as_float(c3 & 0xffff0000u);
    f32x2 s = pkmul(G0, a0);
    s = pkfma(G1, a1, s);
    s = pkfma(G2, a2, s);
    s = pkfma(G3, a3, s);
    return cvtpk(s[0], s[1]);
}

__device__ __forceinline__ void gll16(const void* g, void* l) {
    __builtin_amdgcn_global_load_lds((const unsigned int*)g, (unsigned int*)l, 16, 0, 0);
}

// ---------------- prep: weights -> bf16, K reordered to tap*128+c ----------------
__global__ __launch_bounds__(256) void prep_w(const float* __restrict__ w1,
                                              const float* __restrict__ w2,
                                              unsigned short* __restrict__ w1t,
                                              unsigned short* __restrict__ w2t) {
    int i = blockIdx.x * 256 + threadIdx.x;
    const float* src = w1;
    unsigned short* dst = w1t;
    int j = i;
    if (i >= 147456) { j = i - 147456; src = w2; dst = w2t; }
    int o = j / 1152, rem = j % 1152;
    int c = rem / 9, tap = rem % 9;
    unsigned u = __float_as_uint(src[j]);
    u = (u + 0x7fffu + ((u >> 16) & 1u)) >> 16;
    dst[o * 1152 + tap * 128 + c] = (unsigned short)u;
}

__global__ __launch_bounds__(256) void bn_prep(const float* g1, const float* b1, const float* m1, const float* v1,
                                               const float* g2, const float* b2, const float* m2, const float* v2,
                                               float* inv1, float* sh1, float* inv2, float* sh2) {
    int t = threadIdx.x;
    if (t < 128) {
        float iv = g1[t] * rsqrtf(v1[t] + 1e-5f);
        inv1[t] = iv; sh1[t] = b1[t] - m1[t] * iv;
    } else {
        int u = t - 128;
        float iv = g2[u] * rsqrtf(v2[u] + 1e-5f);
        inv2[u] = iv; sh2[u] = b2[u] - m2[u] * iv;
    }
}

// ---------------- x NCHW fp32 -> NHWC bf16 (32x32 tiles) ----------------
__global__ __launch_bounds__(256) void nhwc_k(const float* __restrict__ x,
                                              unsigned short* __restrict__ xh) {
    __shared__ unsigned short tile[32][36];
    int blk = blockIdx.x;
    int wt = blk & 3, ct = (blk >> 2) & 3, h = (blk >> 4) & 127, b = blk >> 11;
    int t = threadIdx.x;
    int c = t >> 3, seg = t & 7;
    const float* srcp = x + ((size_t)((b * 128 + ct * 32 + c) * 128 + h) * 128) + wt * 32 + seg * 4;
    float4 v = *(const float4*)srcp;
    uint2 pk;
    pk.x = pack_bf16(v.x, v.y);
    pk.y = pack_bf16(v.z, v.w);
    *(uint2*)&tile[c][seg * 4] = pk;
    __syncthreads();
    int w = t >> 3, s2 = t & 7;
    unsigned a0 = tile[s2 * 4 + 0][w];
    unsigned a1 = tile[s2 * 4 + 1][w];
    unsigned a2 = tile[s2 * 4 + 2][w];
    unsigned a3 = tile[s2 * 4 + 3][w];
    uint2 o;
    o.x = (a1 << 16) | a0;
    o.y = (a3 << 16) | a2;
    *(uint2*)(xh + ((size_t)((b * 128 + h) * 128 + wt * 32 + w) * 128) + ct * 32 + s2 * 4) = o;
}

// ---------------- zero only the halo border of the intermediate buffer ----------------
__global__ __launch_bounds__(256) void border_k(unsigned short* __restrict__ o1p) {
    int i = blockIdx.x * 256 + threadIdx.x;   // 4 * 516 * 16 = 33024
    if (i >= 33024) return;
    int chunk = i & 15;
    int pos = i >> 4;
    int b = pos / 516;
    int r = pos % 516;
    int row, col;
    if (r < 130)      { row = 0;   col = r; }
    else if (r < 260) { row = 129; col = r - 130; }
    else { int j = r - 260; row = 1 + (j >> 1); col = (j & 1) * 129; }
    uint4 z = {0u, 0u, 0u, 0u};
    *(uint4*)((char*)o1p + (size_t)((b * 130 + row) * 130 + col) * 256 + chunk * 16) = z;
}

// ---------------- GEMM1: deformable gather + 32x32x16 MFMA + BN1 + ReLU -> halo NHWC bf16 ----------------
// 512 threads, 8 waves = 2 wo x 4 wp; wave owns [64 o x 32 p]. Block = one (b,h) row.
__global__ __launch_bounds__(512, 4) void gemm1_k(
    const unsigned short* __restrict__ xh,
    const float* __restrict__ off,
    const unsigned short* __restrict__ w1t,
    const float* __restrict__ inv1,
    const float* __restrict__ sh1,
    unsigned short* __restrict__ out1p) {
    __shared__ __align__(16) char ldsw[32768];   // weight tile [128 o][16 chunks] 4-bit-XOR swizzled
    __shared__ __align__(16) char ldsv[32768];   // val tile [128 p][16 chunks] 4-bit-XOR swizzled

    int bid = blockIdx.x;
    int swz = ((bid & 7) << 6) | (bid >> 3);
    int h = swz & 127, b = swz >> 7;
    int tid = threadIdx.x, lane = tid & 63, wv = tid >> 6;
    int wo = wv >> 2, wp = wv & 3;
    int lp = lane & 31, hi = lane >> 5;
    int pg = tid & 127;      // gather position
    int cg = tid >> 7;       // gather chunk-group (0..3), 4 chunks of 16B each
    int bH = b * H_;
    const char* xb8 = (const char*)xh;

    f32x16 acc0 = {};
    f32x16 acc1 = {};

    int aRow0 = (wo * 64 + lp) * 256;
    int aRow1 = aRow0 + 32 * 256;
    int bRow  = (wp * 32 + lp) * 256;
    int lsw   = lp & 15;

#define LOADJ(b0, b1, b2, b3, j) do { \
    b0 = *(const uint4*)(xb8 + P0 + (j) * 16); \
    b1 = *(const uint4*)(xb8 + P1 + (j) * 16); \
    b2 = *(const uint4*)(xb8 + P2 + (j) * 16); \
    b3 = *(const uint4*)(xb8 + P3 + (j) * 16); \
} while (0)

#define BSTJ(j, b0, b1, b2, b3) do { \
    uint4 st_; \
    st_.x = blend_pk(b0.x, b1.x, b2.x, b3.x, G0, G1, G2, G3); \
    st_.y = blend_pk(b0.y, b1.y, b2.y, b3.y, G0, G1, G2, G3); \
    st_.z = blend_pk(b0.z, b1.z, b2.z, b3.z, G0, G1, G2, G3); \
    st_.w = blend_pk(b0.w, b1.w, b2.w, b3.w, G0, G1, G2, G3); \
    int ch_ = cg * 4 + (j); \
    *(uint4*)(ldsv + pg * 256 + ((ch_ ^ (pg & 15)) << 4)) = st_; \
} while (0)

    for (int tap = 0; tap < 9; ++tap) {
        __syncthreads();   // all waves done reading ldsw/ldsv of previous tap
        // stage weight tile (linear LDS dest, inverse-swizzled source)
        #pragma unroll
        for (int it = 0; it < 4; ++it) {
            int ci = it * 512 + tid;
            int o = ci >> 4, q = ci & 15;
            gll16((const char*)w1t + o * 2304 + tap * 256 + ((q ^ (o & 15)) << 4), ldsw + ci * 16);
        }
        // per-thread coordinate (one position per thread)
        int kh = tap / 3 - 1, kw = tap % 3 - 1;
        int dyB = ((b * 18 + 2 * tap) * H_ + h) * W_;
        float dy = off[dyB + pg];
        float dx = off[dyB + HW + pg];
        float py = (float)(h + kh) + dy;
        float px = (float)(pg + kw) + dx;
        float y0f = floorf(py), x0f = floorf(px);
        int y0 = (int)y0f, x0 = (int)x0f;
        float wy1 = py - y0f, wx1 = px - x0f;
        float wy0 = 1.f - wy1, wx0 = 1.f - wx1;
        int y1 = y0 + 1, x1 = x0 + 1;
        float g0 = ((unsigned)y0 < 128u && (unsigned)x0 < 128u) ? wy0 * wx0 : 0.f;
        float g1 = ((unsigned)y0 < 128u && (unsigned)x1 < 128u) ? wy0 * wx1 : 0.f;
        float g2 = ((unsigned)y1 < 128u && (unsigned)x0 < 128u) ? wy1 * wx0 : 0.f;
        float g3 = ((unsigned)y1 < 128u && (unsigned)x1 < 128u) ? wy1 * wx1 : 0.f;
        f32x2 G0, G1, G2, G3;
        G0[0] = g0; G0[1] = g0; G1[0] = g1; G1[1] = g1;
        G2[0] = g2; G2[1] = g2; G3[0] = g3; G3[1] = g3;
        int y0c = min(max(y0, 0), 127), y1c = min(max(y1, 0), 127);
        int x0c = min(max(x0, 0), 127), x1c = min(max(x1, 0), 127);
        unsigned cb = cg * 64;
        unsigned P0 = (unsigned)(((bH + y0c) * W_ + x0c) * 256) + cb;
        unsigned P1 = (unsigned)(((bH + y0c) * W_ + x1c) * 256) + cb;
        unsigned P2 = (unsigned)(((bH + y1c) * W_ + x0c) * 256) + cb;
        unsigned P3 = (unsigned)(((bH + y1c) * W_ + x1c) * 256) + cb;

        // 4 sub-chunks of 16B, 2-deep register pipeline
        uint4 A0, A1, A2, A3, Bq0, Bq1, Bq2, Bq3;
        LOADJ(A0, A1, A2, A3, 0);
        LOADJ(Bq0, Bq1, Bq2, Bq3, 1);
        BSTJ(0, A0, A1, A2, A3);
        LOADJ(A0, A1, A2, A3, 2);
        BSTJ(1, Bq0, Bq1, Bq2, Bq3);
        LOADJ(Bq0, Bq1, Bq2, Bq3, 3);
        BSTJ(2, A0, A1, A2, A3);
        BSTJ(3, Bq0, Bq1, Bq2, Bq3);

        __syncthreads();   // weights staged + val written (barrier drains vmcnt/lgkm)

        #pragma unroll
        for (int ks = 0; ks < 8; ++ks) {
            int q0 = 2 * ks + hi;
            int sl = (q0 ^ lsw) << 4;
            short8 a0 = *(const short8*)(ldsw + aRow0 + sl);
            short8 a1 = *(const short8*)(ldsw + aRow1 + sl);
            short8 bb = *(const short8*)(ldsv + bRow + sl);
            acc0 = __builtin_amdgcn_mfma_f32_32x32x16_bf16(a0, bb, acc0, 0, 0, 0);
            acc1 = __builtin_amdgcn_mfma_f32_32x32x16_bf16(a1, bb, acc1, 0, 0, 0);
        }
    }

#undef LOADJ
#undef BSTJ

    // epilogue: BN1 + ReLU -> bf16, NHWC halo store. D: col(p)=lane&31, row(o)=(r&3)+8*(r>>2)+4*hi
    int p = wp * 32 + lp;
    size_t rowbase = (size_t)((b * 130 + h + 1) * 130 + 1 + p) * 128;
    #pragma unroll
    for (int t = 0; t < 2; ++t) {
        #pragma unroll
        for (int k = 0; k < 4; ++k) {
            int o0 = wo * 64 + t * 32 + k * 8 + hi * 4;
            float4 iv = *(const float4*)(inv1 + o0);
            float4 sv = *(const float4*)(sh1 + o0);
            float e0, e1, e2, e3;
            if (t == 0) {
                e0 = acc0[4 * k + 0]; e1 = acc0[4 * k + 1];
                e2 = acc0[4 * k + 2]; e3 = acc0[4 * k + 3];
            } else {
                e0 = acc1[4 * k + 0]; e1 = acc1[4 * k + 1];
                e2 = acc1[4 * k + 2]; e3 = acc1[4 * k + 3];
            }
            float v0 = fmaxf(fmaf(e0, iv.x, sv.x), 0.f);
            float v1 = fmaxf(fmaf(e1, iv.y, sv.y), 0.f);
            float v2 = fmaxf(fmaf(e2, iv.z, sv.z), 0.f);
            float v3 = fmaxf(fmaf(e3, iv.w, sv.w), 0.f);
            uint2 pk2;
            pk2.x = cvtpk(v0, v1);
            pk2.y = cvtpk(v2, v3);
            *(uint2*)(out1p + rowbase + o0) = pk2;
        }
    }
}

// ---------------- GEMM2: dense 3x3 conv (halo NHWC) + BN2 + residual + ReLU -> NCHW fp32 ----------------
// 512 threads, 8 waves = 2 wo x 4 wp; wave owns [64 o x 32 p].
__global__ __launch_bounds__(512, 4) void gemm2_k(
    const unsigned short* __restrict__ out1p,
    const unsigned short* __restrict__ w2t,
    const float* __restrict__ x,
    const float* __restrict__ inv2,
    const float* __restrict__ sh2,
    float* __restrict__ outp) {
    __shared__ __align__(16) char ldsS[33280];   // input rows [130][16 chunks] swizzled
    __shared__ __align__(16) char ldsw[32768];   // weight tile [128 o][16 chunks] swizzled

    int bid = blockIdx.x;
    int swz = ((bid & 7) << 6) | (bid >> 3);
    int h = swz & 127, b = swz >> 7;
    int tid = threadIdx.x, lane = tid & 63, wv = tid >> 6;
    int wo = wv >> 2, wp = wv & 3;
    int lp = lane & 31, hi = lane >> 5;

    f32x16 acc0 = {};
    f32x16 acc1 = {};

    int aRow0 = (wo * 64 + lp) * 256;
    int aRow1 = aRow0 + 32 * 256;
    int lsw = lp & 15;

    for (int kh = 0; kh < 3; ++kh) {
        __syncthreads();   // prev readers done before overwriting ldsS (and ldsw)
        const char* srow = (const char*)out1p + (size_t)((b * 130 + h + kh) * 130) * 256;
        #pragma unroll
        for (int it = 0; it < 5; ++it) {
            int ci = it * 512 + tid;
            if (ci < 2080) {
                int r = ci >> 4, q = ci & 15;
                gll16(srow + r * 256 + ((q ^ (r & 15)) << 4), ldsS + ci * 16);
            }
        }
        for (int kw = 0; kw < 3; ++kw) {
            if (kw) __syncthreads();   // ldsw readers done
            int tap = kh * 3 + kw;
            #pragma unroll
            for (int it = 0; it < 4; ++it) {
                int ci = it * 512 + tid;
                int o = ci >> 4, q = ci & 15;
                gll16((const char*)w2t + o * 2304 + tap * 256 + ((q ^ (o & 15)) << 4), ldsw + ci * 16);
            }
            __syncthreads();           // ldsS + ldsw staged
            int pr = (wp * 32 + lp + kw) * 256;
            int prw = (wp * 32 + lp + kw) & 15;
            #pragma unroll
            for (int ks = 0; ks < 8; ++ks) {
                int q0 = 2 * ks + hi;
                short8 bb = *(const short8*)(ldsS + pr + ((q0 ^ prw) << 4));
                int sl = (q0 ^ lsw) << 4;
                short8 a0 = *(const short8*)(ldsw + aRow0 + sl);
                short8 a1 = *(const short8*)(ldsw + aRow1 + sl);
                acc0 = __builtin_amdgcn_mfma_f32_32x32x16_bf16(a0, bb, acc0, 0, 0, 0);
                acc1 = __builtin_amdgcn_mfma_f32_32x32x16_bf16(a1, bb, acc1, 0, 0, 0);
            }
        }
    }

    // epilogue: BN2 + residual + ReLU, NCHW store (32 consecutive p per half-wave)
    int p = wp * 32 + lp;
    #pragma unroll
    for (int t = 0; t < 2; ++t) {
        #pragma unroll
        for (int k = 0; k < 4; ++k) {
            int o0 = wo * 64 + t * 32 + k * 8 + hi * 4;
            #pragma unroll
            for (int i = 0; i < 4; ++i) {
                int o = o0 + i;
                float e = (t == 0) ? acc0[4 * k + i] : acc1[4 * k + i];
                size_t idx = ((size_t)(b * C_ + o) * H_ + h) * W_ + p;
                float val = fmaf(e, inv2[o], sh2[o]) + x[idx];
                outp[idx] = fmaxf(val, 0.f);
            }
        }
    }
}

extern "C" void kernel_launch(void* const* d_in, const int* in_sizes, int n_in,
                              void* d_out, int out_size, void* d_ws, size_t ws_size,
                              hipStream_t stream) {
    const float* x   = (const float*)d_in[0];
    const float* off = (const float*)d_in[1];
    const float* w1  = (const float*)d_in[2];
    const float* g1  = (const float*)d_in[3];
    const float* b1  = (const float*)d_in[4];
    const float* m1  = (const float*)d_in[5];
    const float* v1  = (const float*)d_in[6];
    const float* w2  = (const float*)d_in[7];
    const float* g2  = (const float*)d_in[8];
    const float* b2  = (const float*)d_in[9];
    const float* m2  = (const float*)d_in[10];
    const float* v2  = (const float*)d_in[11];
    float* outp = (float*)d_out;

    char* ws = (char*)d_ws;
    unsigned short* w1t = (unsigned short*)(ws);
    unsigned short* w2t = (unsigned short*)(ws + 294912);
    float* inv1 = (float*)(ws + 589824);
    float* sh1  = (float*)(ws + 590336);
    float* inv2 = (float*)(ws + 590848);
    float* sh2  = (float*)(ws + 591360);
    unsigned short* xh  = (unsigned short*)(ws + 591872);
    unsigned short* o1p = (unsigned short*)(ws + 17369088);

    prep_w<<<1152, 256, 0, stream>>>(w1, w2, w1t, w2t);
    bn_prep<<<1, 256, 0, stream>>>(g1, b1, m1, v1, g2, b2, m2, v2, inv1, sh1, inv2, sh2);
    nhwc_k<<<8192, 256, 0, stream>>>(x, xh);
    border_k<<<129, 256, 0, stream>>>(o1p);
    gemm1_k<<<512, 512, 0, stream>>>(xh, off, w1t, inv1, sh1, o1p);
    gemm2_k<<<512, 512, 0, stream>>>(o1p, w2t, x, inv2, sh2, outp);
}

// Round 7
// 112.691 us; speedup vs baseline: 1.2258x; 1.2258x over previous
//
#include <hip/hip_runtime.h>
#include <stdint.h>

#define B_ 4
#define C_ 128
#define H_ 128
#define W_ 128
#define HW 16384

typedef short short8 __attribute__((ext_vector_type(8)));
typedef float f32x2 __attribute__((ext_vector_type(2)));
typedef float f32x16 __attribute__((ext_vector_type(16)));

__device__ __forceinline__ unsigned pack_bf16(float lo, float hi) {
    unsigned ul = __float_as_uint(lo);
    unsigned uh = __float_as_uint(hi);
    ul = (ul + 0x7fffu + ((ul >> 16) & 1u)) >> 16;
    uh = (uh + 0x7fffu + ((uh >> 16) & 1u)) & 0xffff0000u;
    return uh | ul;
}

__device__ __forceinline__ unsigned cvtpk(float lo, float hi) {
    unsigned r;
    asm("v_cvt_pk_bf16_f32 %0, %1, %2" : "=v"(r) : "v"(lo), "v"(hi));
    return r;
}

__device__ __forceinline__ f32x2 pkmul(f32x2 a, f32x2 b) {
    f32x2 d;
    asm("v_pk_mul_f32 %0, %1, %2" : "=v"(d) : "v"(a), "v"(b));
    return d;
}
__device__ __forceinline__ f32x2 pkfma(f32x2 a, f32x2 b, f32x2 c) {
    f32x2 d;
    asm("v_pk_fma_f32 %0, %1, %2, %3" : "=v"(d) : "v"(a), "v"(b), "v"(c));
    return d;
}

__device__ __forceinline__ unsigned blend_pk(unsigned c0, unsigned c1, unsigned c2, unsigned c3,
                                             f32x2 G0, f32x2 G1, f32x2 G2, f32x2 G3) {
    f32x2 a0, a1, a2, a3;
    a0[0] = __uint_as_float(c0 << 16); a0[1] = __uint_as_float(c0 & 0xffff0000u);
    a1[0] = __uint_as_float(c1 << 16); a1[1] = __uint_as_float(c1 & 0xffff0000u);
    a2[0] = __uint_as_float(c2 << 16); a2[1] = __uint_as_float(c2 & 0xffff0000u);
    a3[0] = __uint_as_float(c3 << 16); a3[1] = __uint_as_float(c3 & 0xffff0000u);
    f32x2 s = pkmul(G0, a0);
    s = pkfma(G1, a1, s);
    s = pkfma(G2, a2, s);
    s = pkfma(G3, a3, s);
    return cvtpk(s[0], s[1]);
}

__device__ __forceinline__ void gll16(const void* g, void* l) {
    __builtin_amdgcn_global_load_lds((const unsigned int*)g, (unsigned int*)l, 16, 0, 0);
}

// ---------------- prep: weights -> bf16, K reordered to tap*128+c ----------------
__global__ __launch_bounds__(256) void prep_w(const float* __restrict__ w1,
                                              const float* __restrict__ w2,
                                              unsigned short* __restrict__ w1t,
                                              unsigned short* __restrict__ w2t) {
    int i = blockIdx.x * 256 + threadIdx.x;
    const float* src = w1;
    unsigned short* dst = w1t;
    int j = i;
    if (i >= 147456) { j = i - 147456; src = w2; dst = w2t; }
    int o = j / 1152, rem = j % 1152;
    int c = rem / 9, tap = rem % 9;
    unsigned u = __float_as_uint(src[j]);
    u = (u + 0x7fffu + ((u >> 16) & 1u)) >> 16;
    dst[o * 1152 + tap * 128 + c] = (unsigned short)u;
}

__global__ __launch_bounds__(256) void bn_prep(const float* g1, const float* b1, const float* m1, const float* v1,
                                               const float* g2, const float* b2, const float* m2, const float* v2,
                                               float* inv1, float* sh1, float* inv2, float* sh2) {
    int t = threadIdx.x;
    if (t < 128) {
        float iv = g1[t] * rsqrtf(v1[t] + 1e-5f);
        inv1[t] = iv; sh1[t] = b1[t] - m1[t] * iv;
    } else {
        int u = t - 128;
        float iv = g2[u] * rsqrtf(v2[u] + 1e-5f);
        inv2[u] = iv; sh2[u] = b2[u] - m2[u] * iv;
    }
}

// ---------------- x NCHW fp32 -> NHWC bf16 (32x32 tiles) ----------------
__global__ __launch_bounds__(256) void nhwc_k(const float* __restrict__ x,
                                              unsigned short* __restrict__ xh) {
    __shared__ unsigned short tile[32][36];
    int blk = blockIdx.x;
    int wt = blk & 3, ct = (blk >> 2) & 3, h = (blk >> 4) & 127, b = blk >> 11;
    int t = threadIdx.x;
    int c = t >> 3, seg = t & 7;
    const float* srcp = x + ((size_t)((b * 128 + ct * 32 + c) * 128 + h) * 128) + wt * 32 + seg * 4;
    float4 v = *(const float4*)srcp;
    uint2 pk;
    pk.x = pack_bf16(v.x, v.y);
    pk.y = pack_bf16(v.z, v.w);
    *(uint2*)&tile[c][seg * 4] = pk;
    __syncthreads();
    int w = t >> 3, s2 = t & 7;
    unsigned a0 = tile[s2 * 4 + 0][w];
    unsigned a1 = tile[s2 * 4 + 1][w];
    unsigned a2 = tile[s2 * 4 + 2][w];
    unsigned a3 = tile[s2 * 4 + 3][w];
    uint2 o;
    o.x = (a1 << 16) | a0;
    o.y = (a3 << 16) | a2;
    *(uint2*)(xh + ((size_t)((b * 128 + h) * 128 + wt * 32 + w) * 128) + ct * 32 + s2 * 4) = o;
}

// ---------------- zero only the halo border of the intermediate buffer ----------------
__global__ __launch_bounds__(256) void border_k(unsigned short* __restrict__ o1p) {
    int i = blockIdx.x * 256 + threadIdx.x;   // 4 * 516 * 16 = 33024
    if (i >= 33024) return;
    int chunk = i & 15;
    int pos = i >> 4;
    int b = pos / 516;
    int r = pos % 516;
    int row, col;
    if (r < 130)      { row = 0;   col = r; }
    else if (r < 260) { row = 129; col = r - 130; }
    else { int j = r - 260; row = 1 + (j >> 1); col = (j & 1) * 129; }
    uint4 z = {0u, 0u, 0u, 0u};
    *(uint4*)((char*)o1p + (size_t)((b * 130 + row) * 130 + col) * 256 + chunk * 16) = z;
}

// ---------------- GEMM1: deformable gather (coalesced) + 32x32x16 MFMA + BN1 + ReLU ----------------
// 512 threads, 8 waves = 2 wo x 4 wp; wave owns [64 o x 32 p]. Block = one (b,h) row.
__global__ __launch_bounds__(512, 4) void gemm1_k(
    const unsigned short* __restrict__ xh,
    const float* __restrict__ off,
    const unsigned short* __restrict__ w1t,
    const float* __restrict__ inv1,
    const float* __restrict__ sh1,
    unsigned short* __restrict__ out1p) {
    __shared__ __align__(16) char ldsw[32768];   // weight tile [128 o][16 chunks] 4-bit-XOR swizzled
    __shared__ __align__(16) char ldsv[32768];   // val tile [128 p][16 chunks] 4-bit-XOR swizzled

    int bid = blockIdx.x;
    int swz = ((bid & 7) << 6) | (bid >> 3);
    int h = swz & 127, b = swz >> 7;
    int tid = threadIdx.x, lane = tid & 63, wv = tid >> 6;
    int wo = wv >> 2, wp = wv & 3;
    int lp = lane & 31, hi = lane >> 5;
    int prow = tid >> 4;     // gather row group (0..31); positions prow + 32*c
    int seg = tid & 15;      // channel chunk (16B = 8ch)
    int sb = seg * 16;
    int bH = b * H_;
    const char* xb8 = (const char*)xh;

    f32x16 acc0 = {};
    f32x16 acc1 = {};

    int aRow0 = (wo * 64 + lp) * 256;
    int aRow1 = aRow0 + 32 * 256;
    int bRow  = (wp * 32 + lp) * 256;
    int lsw   = lp & 15;

#define COORD(c, P, G) do { \
    int p_ = prow + (c) * 32; \
    float dy_ = off[dyB + p_]; \
    float dx_ = off[dyB + HW + p_]; \
    float py_ = (float)(h + kh) + dy_; \
    float px_ = (float)(p_ + kw) + dx_; \
    float y0f_ = floorf(py_), x0f_ = floorf(px_); \
    int y0_ = (int)y0f_, x0_ = (int)x0f_; \
    float wy1_ = py_ - y0f_, wx1_ = px_ - x0f_; \
    float wy0_ = 1.f - wy1_, wx0_ = 1.f - wx1_; \
    int y1_ = y0_ + 1, x1_ = x0_ + 1; \
    float g0_ = ((unsigned)y0_ < 128u && (unsigned)x0_ < 128u) ? wy0_ * wx0_ : 0.f; \
    float g1_ = ((unsigned)y0_ < 128u && (unsigned)x1_ < 128u) ? wy0_ * wx1_ : 0.f; \
    float g2_ = ((unsigned)y1_ < 128u && (unsigned)x0_ < 128u) ? wy1_ * wx0_ : 0.f; \
    float g3_ = ((unsigned)y1_ < 128u && (unsigned)x1_ < 128u) ? wy1_ * wx1_ : 0.f; \
    G[0][0] = g0_; G[0][1] = g0_; G[1][0] = g1_; G[1][1] = g1_; \
    G[2][0] = g2_; G[2][1] = g2_; G[3][0] = g3_; G[3][1] = g3_; \
    int y0c_ = min(max(y0_, 0), 127), y1c_ = min(max(y1_, 0), 127); \
    int x0c_ = min(max(x0_, 0), 127), x1c_ = min(max(x1_, 0), 127); \
    int r0_ = (bH + y0c_) * W_, r1_ = (bH + y1c_) * W_; \
    P[0] = (unsigned)((r0_ + x0c_) * 256) + sb; \
    P[1] = (unsigned)((r0_ + x1c_) * 256) + sb; \
    P[2] = (unsigned)((r1_ + x0c_) * 256) + sb; \
    P[3] = (unsigned)((r1_ + x1c_) * 256) + sb; \
} while (0)

#define ISSUE(buf, P) do { \
    buf[0] = *(const uint4*)(xb8 + P[0]); \
    buf[1] = *(const uint4*)(xb8 + P[1]); \
    buf[2] = *(const uint4*)(xb8 + P[2]); \
    buf[3] = *(const uint4*)(xb8 + P[3]); \
} while (0)

#define BSTJ(c, buf, G) do { \
    uint4 st_; \
    st_.x = blend_pk(buf[0].x, buf[1].x, buf[2].x, buf[3].x, G[0], G[1], G[2], G[3]); \
    st_.y = blend_pk(buf[0].y, buf[1].y, buf[2].y, buf[3].y, G[0], G[1], G[2], G[3]); \
    st_.z = blend_pk(buf[0].z, buf[1].z, buf[2].z, buf[3].z, G[0], G[1], G[2], G[3]); \
    st_.w = blend_pk(buf[0].w, buf[1].w, buf[2].w, buf[3].w, G[0], G[1], G[2], G[3]); \
    int row_ = prow + (c) * 32; \
    *(uint4*)(ldsv + row_ * 256 + ((seg ^ (row_ & 15)) << 4)) = st_; \
} while (0)

    for (int tap = 0; tap < 9; ++tap) {
        __syncthreads();   // all waves done reading ldsw/ldsv of previous tap
        // stage weight tile (linear LDS dest, inverse-swizzled source)
        #pragma unroll
        for (int it = 0; it < 4; ++it) {
            int ci = it * 512 + tid;
            int o = ci >> 4, q = ci & 15;
            gll16((const char*)w1t + o * 2304 + tap * 256 + ((q ^ (o & 15)) << 4), ldsw + ci * 16);
        }
        int kh = tap / 3 - 1, kw = tap % 3 - 1;
        int dyB = ((b * 18 + 2 * tap) * H_ + h) * W_;

        // coalesced gather: 4 positions x 16 segs per wave-instr, 2-deep pipeline
        uint4 bufA[4], bufB[4];
        unsigned PA[4], PB[4];
        f32x2 GA[4], GB[4];
        COORD(0, PA, GA); ISSUE(bufA, PA);
        COORD(1, PB, GB); ISSUE(bufB, PB);
        BSTJ(0, bufA, GA);
        COORD(2, PA, GA); ISSUE(bufA, PA);
        BSTJ(1, bufB, GB);
        COORD(3, PB, GB); ISSUE(bufB, PB);
        BSTJ(2, bufA, GA);
        BSTJ(3, bufB, GB);

        __syncthreads();   // weights staged + val written (barrier drains vmcnt/lgkm)

        #pragma unroll
        for (int ks = 0; ks < 8; ++ks) {
            int q0 = 2 * ks + hi;
            int sl = (q0 ^ lsw) << 4;
            short8 a0 = *(const short8*)(ldsw + aRow0 + sl);
            short8 a1 = *(const short8*)(ldsw + aRow1 + sl);
            short8 bb = *(const short8*)(ldsv + bRow + sl);
            acc0 = __builtin_amdgcn_mfma_f32_32x32x16_bf16(a0, bb, acc0, 0, 0, 0);
            acc1 = __builtin_amdgcn_mfma_f32_32x32x16_bf16(a1, bb, acc1, 0, 0, 0);
        }
    }

#undef COORD
#undef ISSUE
#undef BSTJ

    // epilogue: BN1 + ReLU -> bf16, NHWC halo store. D: col(p)=lane&31, row(o)=(r&3)+8*(r>>2)+4*hi
    int p = wp * 32 + lp;
    size_t rowbase = (size_t)((b * 130 + h + 1) * 130 + 1 + p) * 128;
    #pragma unroll
    for (int t = 0; t < 2; ++t) {
        #pragma unroll
        for (int k = 0; k < 4; ++k) {
            int o0 = wo * 64 + t * 32 + k * 8 + hi * 4;
            float4 iv = *(const float4*)(inv1 + o0);
            float4 sv = *(const float4*)(sh1 + o0);
            float e0, e1, e2, e3;
            if (t == 0) {
                e0 = acc0[4 * k + 0]; e1 = acc0[4 * k + 1];
                e2 = acc0[4 * k + 2]; e3 = acc0[4 * k + 3];
            } else {
                e0 = acc1[4 * k + 0]; e1 = acc1[4 * k + 1];
                e2 = acc1[4 * k + 2]; e3 = acc1[4 * k + 3];
            }
            float v0 = fmaxf(fmaf(e0, iv.x, sv.x), 0.f);
            float v1 = fmaxf(fmaf(e1, iv.y, sv.y), 0.f);
            float v2 = fmaxf(fmaf(e2, iv.z, sv.z), 0.f);
            float v3 = fmaxf(fmaf(e3, iv.w, sv.w), 0.f);
            uint2 pk2;
            pk2.x = cvtpk(v0, v1);
            pk2.y = cvtpk(v2, v3);
            *(uint2*)(out1p + rowbase + o0) = pk2;
        }
    }
}

// ---------------- GEMM2: dense 3x3 conv (halo NHWC) + BN2 + residual + ReLU -> NCHW fp32 ----------------
// 512 threads, 8 waves = 2 wo x 4 wp; wave owns [64 o x 32 p].
__global__ __launch_bounds__(512, 4) void gemm2_k(
    const unsigned short* __restrict__ out1p,
    const unsigned short* __restrict__ w2t,
    const float* __restrict__ x,
    const float* __restrict__ inv2,
    const float* __restrict__ sh2,
    float* __restrict__ outp) {
    __shared__ __align__(16) char ldsS[33280];   // input rows [130][16 chunks] swizzled
    __shared__ __align__(16) char ldsw[32768];   // weight tile [128 o][16 chunks] swizzled

    int bid = blockIdx.x;
    int swz = ((bid & 7) << 6) | (bid >> 3);
    int h = swz & 127, b = swz >> 7;
    int tid = threadIdx.x, lane = tid & 63, wv = tid >> 6;
    int wo = wv >> 2, wp = wv & 3;
    int lp = lane & 31, hi = lane >> 5;

    f32x16 acc0 = {};
    f32x16 acc1 = {};

    int aRow0 = (wo * 64 + lp) * 256;
    int aRow1 = aRow0 + 32 * 256;
    int lsw = lp & 15;

    for (int kh = 0; kh < 3; ++kh) {
        __syncthreads();   // prev readers done before overwriting ldsS (and ldsw)
        const char* srow = (const char*)out1p + (size_t)((b * 130 + h + kh) * 130) * 256;
        #pragma unroll
        for (int it = 0; it < 5; ++it) {
            int ci = it * 512 + tid;
            if (ci < 2080) {
                int r = ci >> 4, q = ci & 15;
                gll16(srow + r * 256 + ((q ^ (r & 15)) << 4), ldsS + ci * 16);
            }
        }
        for (int kw = 0; kw < 3; ++kw) {
            if (kw) __syncthreads();   // ldsw readers done
            int tap = kh * 3 + kw;
            #pragma unroll
            for (int it = 0; it < 4; ++it) {
                int ci = it * 512 + tid;
                int o = ci >> 4, q = ci & 15;
                gll16((const char*)w2t + o * 2304 + tap * 256 + ((q ^ (o & 15)) << 4), ldsw + ci * 16);
            }
            __syncthreads();           // ldsS + ldsw staged
            int pr = (wp * 32 + lp + kw) * 256;
            int prw = (wp * 32 + lp + kw) & 15;
            #pragma unroll
            for (int ks = 0; ks < 8; ++ks) {
                int q0 = 2 * ks + hi;
                short8 bb = *(const short8*)(ldsS + pr + ((q0 ^ prw) << 4));
                int sl = (q0 ^ lsw) << 4;
                short8 a0 = *(const short8*)(ldsw + aRow0 + sl);
                short8 a1 = *(const short8*)(ldsw + aRow1 + sl);
                acc0 = __builtin_amdgcn_mfma_f32_32x32x16_bf16(a0, bb, acc0, 0, 0, 0);
                acc1 = __builtin_amdgcn_mfma_f32_32x32x16_bf16(a1, bb, acc1, 0, 0, 0);
            }
        }
    }

    // epilogue: BN2 + residual + ReLU, NCHW store (32 consecutive p per half-wave)
    int p = wp * 32 + lp;
    #pragma unroll
    for (int t = 0; t < 2; ++t) {
        #pragma unroll
        for (int k = 0; k < 4; ++k) {
            int o0 = wo * 64 + t * 32 + k * 8 + hi * 4;
            #pragma unroll
            for (int i = 0; i < 4; ++i) {
                int o = o0 + i;
                float e = (t == 0) ? acc0[4 * k + i] : acc1[4 * k + i];
                size_t idx = ((size_t)(b * C_ + o) * H_ + h) * W_ + p;
                float val = fmaf(e, inv2[o], sh2[o]) + x[idx];
                outp[idx] = fmaxf(val, 0.f);
            }
        }
    }
}

extern "C" void kernel_launch(void* const* d_in, const int* in_sizes, int n_in,
                              void* d_out, int out_size, void* d_ws, size_t ws_size,
                              hipStream_t stream) {
    const float* x   = (const float*)d_in[0];
    const float* off = (const float*)d_in[1];
    const float* w1  = (const float*)d_in[2];
    const float* g1  = (const float*)d_in[3];
    const float* b1  = (const float*)d_in[4];
    const float* m1  = (const float*)d_in[5];
    const float* v1  = (const float*)d_in[6];
    const float* w2  = (const float*)d_in[7];
    const float* g2  = (const float*)d_in[8];
    const float* b2  = (const float*)d_in[9];
    const float* m2  = (const float*)d_in[10];
    const float* v2  = (const float*)d_in[11];
    float* outp = (float*)d_out;

    char* ws = (char*)d_ws;
    unsigned short* w1t = (unsigned short*)(ws);
    unsigned short* w2t = (unsigned short*)(ws + 294912);
    float* inv1 = (float*)(ws + 589824);
    float* sh1  = (float*)(ws + 590336);
    float* inv2 = (float*)(ws + 590848);
    float* sh2  = (float*)(ws + 591360);
    unsigned short* xh  = (unsigned short*)(ws + 591872);
    unsigned short* o1p = (unsigned short*)(ws + 17369088);

    prep_w<<<1152, 256, 0, stream>>>(w1, w2, w1t, w2t);
    bn_prep<<<1, 256, 0, stream>>>(g1, b1, m1, v1, g2, b2, m2, v2, inv1, sh1, inv2, sh2);
    nhwc_k<<<8192, 256, 0, stream>>>(x, xh);
    border_k<<<129, 256, 0, stream>>>(o1p);
    gemm1_k<<<512, 512, 0, stream>>>(xh, off, w1t, inv1, sh1, o1p);
    gemm2_k<<<512, 512, 0, stream>>>(o1p, w2t, x, inv2, sh2, outp);
}

// Round 8
// 111.237 us; speedup vs baseline: 1.2418x; 1.0131x over previous
//
#include <hip/hip_runtime.h>
#include <stdint.h>

#define B_ 4
#define C_ 128
#define H_ 128
#define W_ 128
#define HW 16384

typedef short short8 __attribute__((ext_vector_type(8)));
typedef float f32x2 __attribute__((ext_vector_type(2)));
typedef float f32x16 __attribute__((ext_vector_type(16)));

__device__ __forceinline__ unsigned pack_bf16(float lo, float hi) {
    unsigned ul = __float_as_uint(lo);
    unsigned uh = __float_as_uint(hi);
    ul = (ul + 0x7fffu + ((ul >> 16) & 1u)) >> 16;
    uh = (uh + 0x7fffu + ((uh >> 16) & 1u)) & 0xffff0000u;
    return uh | ul;
}

__device__ __forceinline__ unsigned cvtpk(float lo, float hi) {
    unsigned r;
    asm("v_cvt_pk_bf16_f32 %0, %1, %2" : "=v"(r) : "v"(lo), "v"(hi));
    return r;
}

__device__ __forceinline__ f32x2 pkmul(f32x2 a, f32x2 b) {
    f32x2 d;
    asm("v_pk_mul_f32 %0, %1, %2" : "=v"(d) : "v"(a), "v"(b));
    return d;
}
__device__ __forceinline__ f32x2 pkfma(f32x2 a, f32x2 b, f32x2 c) {
    f32x2 d;
    asm("v_pk_fma_f32 %0, %1, %2, %3" : "=v"(d) : "v"(a), "v"(b), "v"(c));
    return d;
}

__device__ __forceinline__ float u2f_lo(unsigned u) { return __uint_as_float(u << 16); }
__device__ __forceinline__ float u2f_hi(unsigned u) { return __uint_as_float(u & 0xffff0000u); }

__device__ __forceinline__ unsigned blend_pk(unsigned c0, unsigned c1, unsigned c2, unsigned c3,
                                             f32x2 G0, f32x2 G1, f32x2 G2, f32x2 G3) {
    f32x2 a0, a1, a2, a3;
    a0[0] = __uint_as_float(c0 << 16); a0[1] = __uint_as_float(c0 & 0xffff0000u);
    a1[0] = __uint_as_float(c1 << 16); a1[1] = __uint_as_float(c1 & 0xffff0000u);
    a2[0] = __uint_as_float(c2 << 16); a2[1] = __uint_as_float(c2 & 0xffff0000u);
    a3[0] = __uint_as_float(c3 << 16); a3[1] = __uint_as_float(c3 & 0xffff0000u);
    f32x2 s = pkmul(G0, a0);
    s = pkfma(G1, a1, s);
    s = pkfma(G2, a2, s);
    s = pkfma(G3, a3, s);
    return cvtpk(s[0], s[1]);
}

__device__ __forceinline__ void gll16(const void* g, void* l) {
    __builtin_amdgcn_global_load_lds((const unsigned int*)g, (unsigned int*)l, 16, 0, 0);
}

// ---------------- prep: weights -> bf16, K reordered to tap*128+c ----------------
__global__ __launch_bounds__(256) void prep_w(const float* __restrict__ w1,
                                              const float* __restrict__ w2,
                                              unsigned short* __restrict__ w1t,
                                              unsigned short* __restrict__ w2t) {
    int i = blockIdx.x * 256 + threadIdx.x;
    const float* src = w1;
    unsigned short* dst = w1t;
    int j = i;
    if (i >= 147456) { j = i - 147456; src = w2; dst = w2t; }
    int o = j / 1152, rem = j % 1152;
    int c = rem / 9, tap = rem % 9;
    unsigned u = __float_as_uint(src[j]);
    u = (u + 0x7fffu + ((u >> 16) & 1u)) >> 16;
    dst[o * 1152 + tap * 128 + c] = (unsigned short)u;
}

__global__ __launch_bounds__(256) void bn_prep(const float* g1, const float* b1, const float* m1, const float* v1,
                                               const float* g2, const float* b2, const float* m2, const float* v2,
                                               float* inv1, float* sh1, float* inv2, float* sh2) {
    int t = threadIdx.x;
    if (t < 128) {
        float iv = g1[t] * rsqrtf(v1[t] + 1e-5f);
        inv1[t] = iv; sh1[t] = b1[t] - m1[t] * iv;
    } else {
        int u = t - 128;
        float iv = g2[u] * rsqrtf(v2[u] + 1e-5f);
        inv2[u] = iv; sh2[u] = b2[u] - m2[u] * iv;
    }
}

// ---------------- x NCHW fp32 -> NHWC bf16 (32x32 tiles) ----------------
__global__ __launch_bounds__(256) void nhwc_k(const float* __restrict__ x,
                                              unsigned short* __restrict__ xh) {
    __shared__ unsigned short tile[32][36];
    int blk = blockIdx.x;
    int wt = blk & 3, ct = (blk >> 2) & 3, h = (blk >> 4) & 127, b = blk >> 11;
    int t = threadIdx.x;
    int c = t >> 3, seg = t & 7;
    const float* srcp = x + ((size_t)((b * 128 + ct * 32 + c) * 128 + h) * 128) + wt * 32 + seg * 4;
    float4 v = *(const float4*)srcp;
    uint2 pk;
    pk.x = pack_bf16(v.x, v.y);
    pk.y = pack_bf16(v.z, v.w);
    *(uint2*)&tile[c][seg * 4] = pk;
    __syncthreads();
    int w = t >> 3, s2 = t & 7;
    unsigned a0 = tile[s2 * 4 + 0][w];
    unsigned a1 = tile[s2 * 4 + 1][w];
    unsigned a2 = tile[s2 * 4 + 2][w];
    unsigned a3 = tile[s2 * 4 + 3][w];
    uint2 o;
    o.x = (a1 << 16) | a0;
    o.y = (a3 << 16) | a2;
    *(uint2*)(xh + ((size_t)((b * 128 + h) * 128 + wt * 32 + w) * 128) + ct * 32 + s2 * 4) = o;
}

// ---------------- zero only the halo border of the intermediate buffer ----------------
__global__ __launch_bounds__(256) void border_k(unsigned short* __restrict__ o1p) {
    int i = blockIdx.x * 256 + threadIdx.x;   // 4 * 516 * 16 = 33024
    if (i >= 33024) return;
    int chunk = i & 15;
    int pos = i >> 4;
    int b = pos / 516;
    int r = pos % 516;
    int row, col;
    if (r < 130)      { row = 0;   col = r; }
    else if (r < 260) { row = 129; col = r - 130; }
    else { int j = r - 260; row = 1 + (j >> 1); col = (j & 1) * 129; }
    uint4 z = {0u, 0u, 0u, 0u};
    *(uint4*)((char*)o1p + (size_t)((b * 130 + row) * 130 + col) * 256 + chunk * 16) = z;
}

// ---------------- GEMM1: deformable gather + 32x32x16 MFMA, double-buffered, 1 barrier/tap ----------------
// 512 threads, 8 waves = 2 wo x 4 wp; wave owns [64 o x 32 p]. Block = one (b,h) row.
__global__ __launch_bounds__(512, 2) void gemm1_k(
    const unsigned short* __restrict__ xh,
    const float* __restrict__ off,
    const unsigned short* __restrict__ w1t,
    const float* __restrict__ inv1,
    const float* __restrict__ sh1,
    unsigned short* __restrict__ out1p) {
    __shared__ __align__(16) char ldsw[2][32768];   // weight tiles [128 o][16 chunks], 4-bit-XOR swz
    __shared__ __align__(16) char ldsv[2][32768];   // val tiles [128 p][16 chunks], 4-bit-XOR swz

    int bid = blockIdx.x;
    int swz = ((bid & 7) << 6) | (bid >> 3);
    int h = swz & 127, b = swz >> 7;
    int tid = threadIdx.x, lane = tid & 63, wv = tid >> 6;
    int wo = wv >> 2, wp = wv & 3;
    int lp = lane & 31, hi = lane >> 5;
    int prow = tid >> 4;     // gather row group (0..31); positions prow + 32*c
    int seg = tid & 15;      // channel chunk (16B = 8ch)
    int sb = seg * 16;
    int bH = b * H_;
    const char* xb8 = (const char*)xh;

    f32x16 acc0 = {};
    f32x16 acc1 = {};

    int aRow0 = (wo * 64 + lp) * 256;
    int aRow1 = aRow0 + 32 * 256;
    int bRow  = (wp * 32 + lp) * 256;
    int lsw   = lp & 15;

    float dyR[2][4], dxR[2][4];
    uint4 buf[4][4];
    f32x2 G[4][4];

#define OFFLOAD(TT, P) do { \
    int dyB_ = ((b * 18 + 2 * (TT)) * H_ + h) * W_; \
    _Pragma("unroll") \
    for (int c_ = 0; c_ < 4; ++c_) { \
        int p_ = prow + c_ * 32; \
        dyR[P][c_] = off[dyB_ + p_]; \
        dxR[P][c_] = off[dyB_ + HW + p_]; \
    } \
} while (0)

#define COORD_ISSUE(TT, P) do { \
    int kh_ = (TT) / 3 - 1, kw_ = (TT) % 3 - 1; \
    _Pragma("unroll") \
    for (int c_ = 0; c_ < 4; ++c_) { \
        int p_ = prow + c_ * 32; \
        float py_ = (float)(h + kh_) + dyR[P][c_]; \
        float px_ = (float)(p_ + kw_) + dxR[P][c_]; \
        float y0f_ = floorf(py_), x0f_ = floorf(px_); \
        int y0_ = (int)y0f_, x0_ = (int)x0f_; \
        float wy1_ = py_ - y0f_, wx1_ = px_ - x0f_; \
        float wy0_ = 1.f - wy1_, wx0_ = 1.f - wx1_; \
        int y1_ = y0_ + 1, x1_ = x0_ + 1; \
        float g0_ = ((unsigned)y0_ < 128u && (unsigned)x0_ < 128u) ? wy0_ * wx0_ : 0.f; \
        float g1_ = ((unsigned)y0_ < 128u && (unsigned)x1_ < 128u) ? wy0_ * wx1_ : 0.f; \
        float g2_ = ((unsigned)y1_ < 128u && (unsigned)x0_ < 128u) ? wy1_ * wx0_ : 0.f; \
        float g3_ = ((unsigned)y1_ < 128u && (unsigned)x1_ < 128u) ? wy1_ * wx1_ : 0.f; \
        G[c_][0][0] = g0_; G[c_][0][1] = g0_; \
        G[c_][1][0] = g1_; G[c_][1][1] = g1_; \
        G[c_][2][0] = g2_; G[c_][2][1] = g2_; \
        G[c_][3][0] = g3_; G[c_][3][1] = g3_; \
        int y0c_ = min(max(y0_, 0), 127), y1c_ = min(max(y1_, 0), 127); \
        int x0c_ = min(max(x0_, 0), 127), x1c_ = min(max(x1_, 0), 127); \
        int r0_ = (bH + y0c_) * W_, r1_ = (bH + y1c_) * W_; \
        buf[c_][0] = *(const uint4*)(xb8 + (unsigned)((r0_ + x0c_) * 256) + sb); \
        buf[c_][1] = *(const uint4*)(xb8 + (unsigned)((r0_ + x1c_) * 256) + sb); \
        buf[c_][2] = *(const uint4*)(xb8 + (unsigned)((r1_ + x0c_) * 256) + sb); \
        buf[c_][3] = *(const uint4*)(xb8 + (unsigned)((r1_ + x1c_) * 256) + sb); \
    } \
} while (0)

#define STAGEW(TT, P) do { \
    _Pragma("unroll") \
    for (int it_ = 0; it_ < 4; ++it_) { \
        int ci_ = it_ * 512 + tid; \
        int o_ = ci_ >> 4, q_ = ci_ & 15; \
        gll16((const char*)w1t + o_ * 2304 + (TT) * 256 + ((q_ ^ (o_ & 15)) << 4), &ldsw[P][0] + ci_ * 16); \
    } \
} while (0)

#define BLEND_WR(P) do { \
    _Pragma("unroll") \
    for (int c_ = 0; c_ < 4; ++c_) { \
        uint4 st_; \
        st_.x = blend_pk(buf[c_][0].x, buf[c_][1].x, buf[c_][2].x, buf[c_][3].x, G[c_][0], G[c_][1], G[c_][2], G[c_][3]); \
        st_.y = blend_pk(buf[c_][0].y, buf[c_][1].y, buf[c_][2].y, buf[c_][3].y, G[c_][0], G[c_][1], G[c_][2], G[c_][3]); \
        st_.z = blend_pk(buf[c_][0].z, buf[c_][1].z, buf[c_][2].z, buf[c_][3].z, G[c_][0], G[c_][1], G[c_][2], G[c_][3]); \
        st_.w = blend_pk(buf[c_][0].w, buf[c_][1].w, buf[c_][2].w, buf[c_][3].w, G[c_][0], G[c_][1], G[c_][2], G[c_][3]); \
        int row_ = prow + c_ * 32; \
        *(uint4*)(&ldsv[P][0] + row_ * 256 + ((seg ^ (row_ & 15)) << 4)) = st_; \
    } \
} while (0)

#define MFMA_PHASE(P) do { \
    _Pragma("unroll") \
    for (int ks_ = 0; ks_ < 8; ++ks_) { \
        int q0_ = 2 * ks_ + hi; \
        int sl_ = (q0_ ^ lsw) << 4; \
        short8 a0_ = *(const short8*)(&ldsw[P][0] + aRow0 + sl_); \
        short8 a1_ = *(const short8*)(&ldsw[P][0] + aRow1 + sl_); \
        short8 bb_ = *(const short8*)(&ldsv[P][0] + bRow + sl_); \
        acc0 = __builtin_amdgcn_mfma_f32_32x32x16_bf16(a0_, bb_, acc0, 0, 0, 0); \
        acc1 = __builtin_amdgcn_mfma_f32_32x32x16_bf16(a1_, bb_, acc1, 0, 0, 0); \
    } \
} while (0)

#define TAP_BODY(TT, PAR) do { \
    COORD_ISSUE((TT) + 1, (PAR) ^ 1); \
    if ((TT) + 2 <= 8) OFFLOAD((TT) + 2, PAR); \
    STAGEW((TT) + 1, (PAR) ^ 1); \
    MFMA_PHASE(PAR); \
    BLEND_WR((PAR) ^ 1); \
    __syncthreads(); \
} while (0)

    // ---- prologue: tap 0 into buffers [0] ----
    OFFLOAD(0, 0);
    STAGEW(0, 0);
    COORD_ISSUE(0, 0);
    OFFLOAD(1, 1);
    BLEND_WR(0);
    __syncthreads();

    for (int t = 0; t < 8; t += 2) {
        TAP_BODY(t, 0);
        TAP_BODY(t + 1, 1);
    }
    MFMA_PHASE(0);   // tap 8

#undef OFFLOAD
#undef COORD_ISSUE
#undef STAGEW
#undef BLEND_WR
#undef MFMA_PHASE
#undef TAP_BODY

    // epilogue: BN1 + ReLU -> bf16, NHWC halo store. D: col(p)=lane&31, row(o)=(r&3)+8*(r>>2)+4*hi
    int p = wp * 32 + lp;
    size_t rowbase = (size_t)((b * 130 + h + 1) * 130 + 1 + p) * 128;
    #pragma unroll
    for (int t = 0; t < 2; ++t) {
        #pragma unroll
        for (int k = 0; k < 4; ++k) {
            int o0 = wo * 64 + t * 32 + k * 8 + hi * 4;
            float4 iv = *(const float4*)(inv1 + o0);
            float4 sv = *(const float4*)(sh1 + o0);
            float e0, e1, e2, e3;
            if (t == 0) {
                e0 = acc0[4 * k + 0]; e1 = acc0[4 * k + 1];
                e2 = acc0[4 * k + 2]; e3 = acc0[4 * k + 3];
            } else {
                e0 = acc1[4 * k + 0]; e1 = acc1[4 * k + 1];
                e2 = acc1[4 * k + 2]; e3 = acc1[4 * k + 3];
            }
            float v0 = fmaxf(fmaf(e0, iv.x, sv.x), 0.f);
            float v1 = fmaxf(fmaf(e1, iv.y, sv.y), 0.f);
            float v2 = fmaxf(fmaf(e2, iv.z, sv.z), 0.f);
            float v3 = fmaxf(fmaf(e3, iv.w, sv.w), 0.f);
            uint2 pk2;
            pk2.x = cvtpk(v0, v1);
            pk2.y = cvtpk(v2, v3);
            *(uint2*)(out1p + rowbase + o0) = pk2;
        }
    }
}

// ---------------- GEMM2: dense 3x3 conv (halo NHWC) + BN2 + bf16 residual + ReLU -> NCHW fp32 ----------------
// 512 threads, 8 waves = 2 wo x 4 wp; wave owns [64 o x 32 p].
__global__ __launch_bounds__(512, 4) void gemm2_k(
    const unsigned short* __restrict__ out1p,
    const unsigned short* __restrict__ w2t,
    const unsigned short* __restrict__ xh,
    const float* __restrict__ inv2,
    const float* __restrict__ sh2,
    float* __restrict__ outp) {
    __shared__ __align__(16) char ldsS[33280];   // input rows [130][16 chunks] swizzled
    __shared__ __align__(16) char ldsw[32768];   // weight tile [128 o][16 chunks] swizzled

    int bid = blockIdx.x;
    int swz = ((bid & 7) << 6) | (bid >> 3);
    int h = swz & 127, b = swz >> 7;
    int tid = threadIdx.x, lane = tid & 63, wv = tid >> 6;
    int wo = wv >> 2, wp = wv & 3;
    int lp = lane & 31, hi = lane >> 5;

    f32x16 acc0 = {};
    f32x16 acc1 = {};

    int aRow0 = (wo * 64 + lp) * 256;
    int aRow1 = aRow0 + 32 * 256;
    int lsw = lp & 15;

    for (int kh = 0; kh < 3; ++kh) {
        __syncthreads();   // prev readers done before overwriting ldsS (and ldsw)
        const char* srow = (const char*)out1p + (size_t)((b * 130 + h + kh) * 130) * 256;
        #pragma unroll
        for (int it = 0; it < 5; ++it) {
            int ci = it * 512 + tid;
            if (ci < 2080) {
                int r = ci >> 4, q = ci & 15;
                gll16(srow + r * 256 + ((q ^ (r & 15)) << 4), ldsS + ci * 16);
            }
        }
        for (int kw = 0; kw < 3; ++kw) {
            if (kw) __syncthreads();   // ldsw readers done
            int tap = kh * 3 + kw;
            #pragma unroll
            for (int it = 0; it < 4; ++it) {
                int ci = it * 512 + tid;
                int o = ci >> 4, q = ci & 15;
                gll16((const char*)w2t + o * 2304 + tap * 256 + ((q ^ (o & 15)) << 4), ldsw + ci * 16);
            }
            __syncthreads();           // ldsS + ldsw staged
            int pr = (wp * 32 + lp + kw) * 256;
            int prw = (wp * 32 + lp + kw) & 15;
            #pragma unroll
            for (int ks = 0; ks < 8; ++ks) {
                int q0 = 2 * ks + hi;
                short8 bb = *(const short8*)(ldsS + pr + ((q0 ^ prw) << 4));
                int sl = (q0 ^ lsw) << 4;
                short8 a0 = *(const short8*)(ldsw + aRow0 + sl);
                short8 a1 = *(const short8*)(ldsw + aRow1 + sl);
                acc0 = __builtin_amdgcn_mfma_f32_32x32x16_bf16(a0, bb, acc0, 0, 0, 0);
                acc1 = __builtin_amdgcn_mfma_f32_32x32x16_bf16(a1, bb, acc1, 0, 0, 0);
            }
        }
    }

    // epilogue: BN2 + bf16 residual (from xh) + ReLU, NCHW store
    int p = wp * 32 + lp;
    const unsigned short* xrow = xh + (size_t)((b * 128 + h) * 128 + p) * 128;
    #pragma unroll
    for (int t = 0; t < 2; ++t) {
        #pragma unroll
        for (int k = 0; k < 4; ++k) {
            int o0 = wo * 64 + t * 32 + k * 8 + hi * 4;
            uint2 rx = *(const uint2*)(xrow + o0);
            float x0 = u2f_lo(rx.x), x1 = u2f_hi(rx.x);
            float x2 = u2f_lo(rx.y), x3 = u2f_hi(rx.y);
            float e0, e1, e2, e3;
            if (t == 0) {
                e0 = acc0[4 * k + 0]; e1 = acc0[4 * k + 1];
                e2 = acc0[4 * k + 2]; e3 = acc0[4 * k + 3];
            } else {
                e0 = acc1[4 * k + 0]; e1 = acc1[4 * k + 1];
                e2 = acc1[4 * k + 2]; e3 = acc1[4 * k + 3];
            }
            size_t idx = ((size_t)(b * C_ + o0) * H_ + h) * W_ + p;
            outp[idx]            = fmaxf(fmaf(e0, inv2[o0 + 0], sh2[o0 + 0]) + x0, 0.f);
            outp[idx + HW]       = fmaxf(fmaf(e1, inv2[o0 + 1], sh2[o0 + 1]) + x1, 0.f);
            outp[idx + 2 * HW]   = fmaxf(fmaf(e2, inv2[o0 + 2], sh2[o0 + 2]) + x2, 0.f);
            outp[idx + 3 * HW]   = fmaxf(fmaf(e3, inv2[o0 + 3], sh2[o0 + 3]) + x3, 0.f);
        }
    }
}

extern "C" void kernel_launch(void* const* d_in, const int* in_sizes, int n_in,
                              void* d_out, int out_size, void* d_ws, size_t ws_size,
                              hipStream_t stream) {
    const float* x   = (const float*)d_in[0];
    const float* off = (const float*)d_in[1];
    const float* w1  = (const float*)d_in[2];
    const float* g1  = (const float*)d_in[3];
    const float* b1  = (const float*)d_in[4];
    const float* m1  = (const float*)d_in[5];
    const float* v1  = (const float*)d_in[6];
    const float* w2  = (const float*)d_in[7];
    const float* g2  = (const float*)d_in[8];
    const float* b2  = (const float*)d_in[9];
    const float* m2  = (const float*)d_in[10];
    const float* v2  = (const float*)d_in[11];
    float* outp = (float*)d_out;

    char* ws = (char*)d_ws;
    unsigned short* w1t = (unsigned short*)(ws);
    unsigned short* w2t = (unsigned short*)(ws + 294912);
    float* inv1 = (float*)(ws + 589824);
    float* sh1  = (float*)(ws + 590336);
    float* inv2 = (float*)(ws + 590848);
    float* sh2  = (float*)(ws + 591360);
    unsigned short* xh  = (unsigned short*)(ws + 591872);
    unsigned short* o1p = (unsigned short*)(ws + 17369088);

    prep_w<<<1152, 256, 0, stream>>>(w1, w2, w1t, w2t);
    bn_prep<<<1, 256, 0, stream>>>(g1, b1, m1, v1, g2, b2, m2, v2, inv1, sh1, inv2, sh2);
    nhwc_k<<<8192, 256, 0, stream>>>(x, xh);
    border_k<<<129, 256, 0, stream>>>(o1p);
    gemm1_k<<<512, 512, 0, stream>>>(xh, off, w1t, inv1, sh1, o1p);
    gemm2_k<<<512, 512, 0, stream>>>(o1p, w2t, xh, inv2, sh2, outp);
}